// Round 5
// baseline (551.525 us; speedup 1.0000x reference)
//
#include <hip/hip_runtime.h>
#include <cstdint>
#include <cstddef>

typedef unsigned int u32;
typedef unsigned short u16;

#define NB 64
#define DIN 512
#define UNITS 1024
#define TOPICS 20
#define VOCAB 32000
#define NS_OFF ((size_t)NB * TOPICS * VOCAB)
#define ESV_PART ((size_t)NB * VOCAB)    // floats per k-partial buffer

typedef __attribute__((ext_vector_type(8))) short s16x8;
typedef __attribute__((ext_vector_type(4))) float f32x4;

// ---------- bf16 helpers ----------
__device__ __forceinline__ float bf2f(u16 h) {
    union { u32 u; float f; } c; c.u = ((u32)h) << 16; return c.f;
}
__device__ __forceinline__ u16 f2bf(float f) {
    union { float f; u32 u; } c; c.f = f;
    u32 r = c.u + 0x7FFFu + ((c.u >> 16) & 1u);   // RNE
    return (u16)(r >> 16);
}
template<bool F32>
__device__ __forceinline__ float ldv(const void* p, size_t i) {
    if constexpr (F32) return ((const float*)p)[i];
    else return bf2f(((const u16*)p)[i]);
}
__device__ __forceinline__ float ldr(const void* p, size_t i, bool f32) {
    return f32 ? ((const float*)p)[i] : bf2f(((const u16*)p)[i]);
}

// ---------- threefry2x32-20, key (0,42), partitionable counts (0,i) ----------
__device__ __forceinline__ u32 threefry_bits_partitionable(u32 i) {
    const u32 ks0 = 0u, ks1 = 42u, ks2 = 0u ^ 42u ^ 0x1BD11BDAu;
    u32 x0 = 0u + ks0, x1 = i + ks1;
#define TF_R(r) { x0 += x1; x1 = (x1 << r) | (x1 >> (32 - r)); x1 ^= x0; }
    TF_R(13) TF_R(15) TF_R(26) TF_R(6)
    x0 += ks1; x1 += ks2 + 1u;
    TF_R(17) TF_R(29) TF_R(16) TF_R(24)
    x0 += ks2; x1 += ks0 + 2u;
    TF_R(13) TF_R(15) TF_R(26) TF_R(6)
    x0 += ks0; x1 += ks1 + 3u;
    TF_R(17) TF_R(29) TF_R(16) TF_R(24)
    x0 += ks1; x1 += ks2 + 4u;
    TF_R(13) TF_R(15) TF_R(26) TF_R(6)
    x0 += ks2; x1 += ks0 + 5u;
#undef TF_R
    return x0 ^ x1;
}

// ---------- init: self-detect dtype, eb = exp(beta), zero lsum, publish flag ----------
__global__ __launch_bounds__(256)
void k_init(const void* __restrict__ beta, int* __restrict__ flag,
            float* __restrict__ lsum, float* __restrict__ eb) {
    int tid = threadIdx.x, lane = tid & 63, w = tid >> 6;
    __shared__ int cnt_s[4];
    int cnt = 0;
    const u32* braw = (const u32*)beta;
    for (int i = tid; i < 1024; i += 256) {
        u32 x = braw[i];
        u32 e = (x >> 7) & 0xFFu;
        cnt += (e >= 110u && e <= 132u) ? 1 : 0;
    }
    for (int off = 32; off; off >>= 1) cnt += __shfl_down(cnt, off, 64);
    if (lane == 0) cnt_s[w] = cnt;
    __syncthreads();
    int total = cnt_s[0] + cnt_s[1] + cnt_s[2] + cnt_s[3];
    bool f32 = total < 512;

    size_t base = (size_t)blockIdx.x * 2000;
    for (int i = tid; i < 2000; i += 256)
        eb[base + i] = __expf(ldr(beta, base + i, f32));

    if (blockIdx.x == 0) {
        for (int i = tid; i < NB * TOPICS; i += 256) lsum[i] = 0.f;
        if (tid == 0) flag[0] = f32 ? 1 : 0;
    }
}

// ---------- A: next_state = x@Wxh + h@Whh ----------
template<bool F32>
__device__ void state_body(const void* xin, const void* h0, const void* Wxh,
                           const void* Whh, float* ns_f32, void* dout) {
    __shared__ float lx[DIN + UNITS];
    int b = blockIdx.x >> 2;
    int u = ((blockIdx.x & 3) << 8) | threadIdx.x;
    for (int i = threadIdx.x; i < DIN; i += 256)
        lx[i] = ldv<F32>(xin, (size_t)b * DIN + i);
    for (int i = threadIdx.x; i < UNITS; i += 256)
        lx[DIN + i] = ldv<F32>(h0, (size_t)b * UNITS + i);
    __syncthreads();
    float acc = 0.f;
#pragma unroll 8
    for (int k = 0; k < DIN; ++k)   acc += lx[k]       * ldv<F32>(Wxh, (size_t)k * UNITS + u);
#pragma unroll 8
    for (int k = 0; k < UNITS; ++k) acc += lx[DIN + k] * ldv<F32>(Whh, (size_t)k * UNITS + u);
    int idx = b * UNITS + u;
    ns_f32[idx] = acc;
    if constexpr (F32) ((float*)dout)[NS_OFF + idx] = acc;
    else               ((u16*)dout)[NS_OFF + idx]   = f2bf(acc);
}
__global__ __launch_bounds__(256)
void k_state(const int* __restrict__ flag, const void* xin, const void* h0,
             const void* Wxh, const void* Whh,
             float* __restrict__ ns_f32, void* dout) {
    if (*flag) state_body<true>(xin, h0, Wxh, Whh, ns_f32, dout);
    else       state_body<false>(xin, h0, Wxh, Whh, ns_f32, dout);
}

// ---------- B: coeff_b = 1 - bernoulli_sample ----------
template<bool F32>
__device__ void bern_body(const float* ns, const void* bk, float* coeff) {
    int b = blockIdx.x, lane = threadIdx.x;
    float s = 0.f;
#pragma unroll
    for (int i = 0; i < UNITS / 64; ++i) {
        int k = lane + (i << 6);
        s += ns[b * UNITS + k] * ldv<F32>(bk, k);
    }
    for (int off = 32; off; off >>= 1) s += __shfl_down(s, off, 64);
    if (lane == 0) {
        float sp = log1pf(expf(s));              // softplus
        float p  = 1.f / (1.f + expf(-sp));      // sigmoid
        u32 bits = threefry_bits_partitionable((u32)b);
        union { u32 u; float f; } c; c.u = (bits >> 9) | 0x3f800000u;
        float uni = c.f - 1.0f;
        coeff[b] = (uni < p) ? 0.f : 1.f;        // (1 - sample)
    }
}
__global__ __launch_bounds__(64)
void k_bern(const int* __restrict__ flag, const float* __restrict__ ns,
            const void* bk, float* __restrict__ coeff) {
    if (*flag) bern_body<true>(ns, bk, coeff);
    else       bern_body<false>(ns, bk, coeff);
}

// ============================================================================
// C: logit partials. esv4[kb][b][v] = ns[b][kb*256:(kb+1)*256] @ Wv[...][v]
// (exp is applied downstream in k_sum/k_write, which read esv4 anyway.)
//
// RATIONALE (r1/r2/r4 evidence): three different microstructures all hit
// ~0.6 TB/s reading Wv as 128-256B slices with 64KB row stride -> DRAM
// page-granularity limit, NOT a pipelining problem. Fix = wider contiguous
// chunks: v-tile 256 (512B/row) x k-tile 256, grid 500 = 125v x 4k partials,
// XCD-chunked remap so ~63 v-adjacent blocks share an XCD/L2 (page cluster).
// k-split forced by register budget (64b x 256v f32 acc = cap); partials go
// to 4 disjoint f32 buffers (no atomics), summed downstream.
//   A (64 x 256 bf16, 32KB): loaded ONCE to LDS, +16B row pad -> 2-way (free).
//   B: double-buffered global_load_lds, 16B-chunk XOR source-swizzle
//      (slot = c ^ (k>>3), involution, applied on src and on read) ->
//      ds_read_u16 frags ~2-4-way, LDS not critical.
//   Sync: plain __syncthreads dbuf (m97-proven); this round tests the
//   ACCESS PATTERN, not the sync structure.
// f32 path: session-verified VALU tile (v-tile 64, tile id = pos), writes
// raw logits to part 0 only; downstream skips parts 1-3 when flag=f32.
// ============================================================================
#define PAD 68
#define SV_A_STRIDE 264                        // shorts per A row (528B, 16B-aligned pad)
#define SV_A_BYTES  (64 * SV_A_STRIDE * 2)     // 33792
#define SV_B_BYTES  16384                      // one B stage: 32k x 256v bf16
#define SV_SMEM_BYTES (SV_A_BYTES + 2 * SV_B_BYTES)   // 66560; f32 path needs 34816

__device__ __forceinline__ void gld16(const void* g, void* l) {
    __builtin_amdgcn_global_load_lds(
        (const __attribute__((address_space(1))) void*)g,
        (__attribute__((address_space(3))) void*)l, 16, 0, 0);
}

__device__ void sv_mfma_body(const short* __restrict__ ns16,
                             const short* __restrict__ Wv,
                             float* __restrict__ esv4, char* smem, int pos) {
    short* As = (short*)smem;
    char*  B0 = smem + SV_A_BYTES;
    const int tid  = threadIdx.x;
    const int lane = tid & 63;
    const int wn   = tid >> 6;       // wave 0..3
    const int g    = lane >> 4;      // k-group 0..3
    const int l15  = lane & 15;

    const int vb = pos % 125, kb = pos / 125;
    const int v0 = vb * 256;
    const int kbase0 = kb * 256;

    // ---- A one-time stage: 64 rows x 256 k, padded rows (2-way banks) ----
#pragma unroll
    for (int j = 0; j < 8; ++j) {
        int idx = j * 256 + tid;          // 2048 chunks of 16B
        int row = idx >> 5, c = idx & 31;
        *(s16x8*)&As[row * SV_A_STRIDE + c * 8] =
            *(const s16x8*)&ns16[(size_t)row * UNITS + kbase0 + c * 8];
    }

    // ---- B staging: 1024 chunks of 16B, linear dest, XOR-swizzled source ----
    auto stageB = [&](int t, char* dst) {
        int kbase = kbase0 + t * 32;
#pragma unroll
        for (int p = 0; p < 4; ++p) {
            int ib = p * 256 + wn * 64;   // wave-uniform LDS base index
            int idx = ib + lane;
            int k = idx >> 5, c = idx & 31, s = k >> 3;
            const short* src = Wv + (size_t)(kbase + k) * VOCAB + v0 + ((c ^ s) << 3);
            gld16(src, dst + (size_t)idx * 16);
        }
    };

    f32x4 acc[4][4];
#pragma unroll
    for (int m = 0; m < 4; ++m)
#pragma unroll
        for (int n = 0; n < 4; ++n) acc[m][n] = (f32x4){0.f, 0.f, 0.f, 0.f};

    stageB(0, B0);
    __syncthreads();

#pragma unroll
    for (int t = 0; t < 8; ++t) {
        char* cur = B0 + (t & 1) * SV_B_BYTES;
        if (t < 7) stageB(t + 1, B0 + ((t + 1) & 1) * SV_B_BYTES);

        // A fragments: row = mf*16+l15, k = t*32 + g*8 .. +7
        s16x8 af[4];
#pragma unroll
        for (int mf = 0; mf < 4; ++mf)
            af[mf] = *(const s16x8*)&As[(mf * 16 + l15) * SV_A_STRIDE + t * 32 + g * 8];

        const short* Bs = (const short*)cur;
#pragma unroll
        for (int nf = 0; nf < 4; ++nf) {
            int col = wn * 64 + nf * 16 + l15;
            int b0  = ((col >> 3) ^ g) * 8 + (col & 7);   // swizzled base (shorts)
            s16x8 bf;
#pragma unroll
            for (int e = 0; e < 8; ++e)
                bf[e] = Bs[(g * 8 + e) * 256 + b0];
#pragma unroll
            for (int mf = 0; mf < 4; ++mf)
                acc[mf][nf] = __builtin_amdgcn_mfma_f32_16x16x32_bf16(
                                  af[mf], bf, acc[mf][nf], 0, 0, 0);
        }
        __syncthreads();
    }

    // ---- epilogue: raw logit partial. C/D: row=(lane>>4)*4+r, col=l15 ----
    float* dst = esv4 + (size_t)kb * ESV_PART + v0;
#pragma unroll
    for (int mf = 0; mf < 4; ++mf)
#pragma unroll
        for (int nf = 0; nf < 4; ++nf) {
            int col = wn * 64 + nf * 16 + l15;
#pragma unroll
            for (int r = 0; r < 4; ++r) {
                int b = mf * 16 + (lane >> 4) * 4 + r;
                dst[(size_t)b * VOCAB + col] = acc[mf][nf][r];
            }
        }
}

__device__ void sv_f32_body(const float* __restrict__ ns, const float* __restrict__ Wv,
                            float* __restrict__ esv4, float* As, float* Bs, int pos) {
    int tid = threadIdx.x;
    int vt = tid & 7;           // 8 v-threads x 8 v = 64 v
    int bg = tid >> 3;          // 32 groups x 2 b = 64 b
    int v0 = pos * 64;
    float acc[2][8];
#pragma unroll
    for (int r = 0; r < 2; ++r)
#pragma unroll
        for (int j = 0; j < 8; ++j) acc[r][j] = 0.f;

    for (int k0 = 0; k0 < UNITS; k0 += 64) {
        __syncthreads();
        for (int e = tid; e < 1024; e += 256) {      // stage A: ns[64b][64k]
            int row = e >> 4, c4 = e & 15;
            *(float4*)&As[row * PAD + c4 * 4] =
                *(const float4*)&ns[row * UNITS + k0 + c4 * 4];
        }
        for (int e = tid; e < 1024; e += 256) {      // stage B: Wv[64k][64v]
            int row = e >> 4, c4 = e & 15;
            *(float4*)&Bs[row * PAD + c4 * 4] =
                *(const float4*)(Wv + (size_t)(k0 + row) * VOCAB + v0 + c4 * 4);
        }
        __syncthreads();
#pragma unroll 4
        for (int u = 0; u < 64; u += 4) {
            float4 a0 = *(float4*)&As[(bg * 2 + 0) * PAD + u];
            float4 a1 = *(float4*)&As[(bg * 2 + 1) * PAD + u];
            float aa0[4] = {a0.x, a0.y, a0.z, a0.w};
            float aa1[4] = {a1.x, a1.y, a1.z, a1.w};
#pragma unroll
            for (int uu = 0; uu < 4; ++uu) {
                float4 b0 = *(float4*)&Bs[(u + uu) * PAD + vt * 8];
                float4 b1 = *(float4*)&Bs[(u + uu) * PAD + vt * 8 + 4];
                float bb[8] = {b0.x, b0.y, b0.z, b0.w, b1.x, b1.y, b1.z, b1.w};
#pragma unroll
                for (int j = 0; j < 8; ++j) {
                    acc[0][j] = fmaf(aa0[uu], bb[j], acc[0][j]);
                    acc[1][j] = fmaf(aa1[uu], bb[j], acc[1][j]);
                }
            }
        }
    }
    // raw logits to part 0 (exp applied downstream)
#pragma unroll
    for (int r = 0; r < 2; ++r) {
        float4 e0 = {acc[r][0], acc[r][1], acc[r][2], acc[r][3]};
        float4 e1 = {acc[r][4], acc[r][5], acc[r][6], acc[r][7]};
        float* dst = esv4 + (size_t)(bg * 2 + r) * VOCAB + v0 + vt * 8;
        *(float4*)dst = e0;
        *(float4*)(dst + 4) = e1;
    }
}

__global__ __launch_bounds__(256)
void k_sv(const int* __restrict__ flag, const float* __restrict__ ns,
          const void* Wv, const void* dout, float* __restrict__ esv4) {
    __shared__ __align__(16) char smem[SV_SMEM_BYTES];
    // bijective XCD-chunked remap: same-XCD blocks get consecutive pos
    int lin = blockIdx.x;                     // 0..499
    int xcd = lin & 7, idx = lin >> 3;
    int pos = (xcd < 4) ? xcd * 63 + idx : 252 + (xcd - 4) * 62 + idx;
    if (*flag) {
        float* As = (float*)smem;
        sv_f32_body(ns, (const float*)Wv, esv4, As, As + 64 * PAD, pos);
    } else {
        sv_mfma_body((const short*)dout + NS_OFF, (const short*)Wv, esv4, smem, pos);
    }
}

// ---------- D1: lsum[b][t] = sum_v exp(sum_kb p_kb) * (c ? eb[t][v] : 1) ----------
__global__ __launch_bounds__(256)
void k_sum(const int* __restrict__ flag, const float* __restrict__ esv4,
           const float* __restrict__ eb, const float* __restrict__ coeff,
           float* __restrict__ lsum) {
    int b = blockIdx.y, tid = threadIdx.x;
    bool f32 = (*flag != 0);
    float c = coeff[b];
    const float4* P0 = (const float4*)(esv4 + (size_t)b * VOCAB);
    const float4* P1 = (const float4*)(esv4 + ESV_PART + (size_t)b * VOCAB);
    const float4* P2 = (const float4*)(esv4 + 2 * ESV_PART + (size_t)b * VOCAB);
    const float4* P3 = (const float4*)(esv4 + 3 * ESV_PART + (size_t)b * VOCAB);
    int i0 = blockIdx.x * 256 + tid;
    __shared__ float red[4][TOPICS];
    int lane = tid & 63, w = tid >> 6;

    if (c != 0.f) {
        float acc[TOPICS];
#pragma unroll
        for (int t = 0; t < TOPICS; ++t) acc[t] = 0.f;
        for (int i = i0; i < VOCAB / 4; i += 4096) {
            float4 q = P0[i];
            if (!f32) {
                float4 a = P1[i], d = P2[i], h = P3[i];
                q.x += a.x + d.x + h.x; q.y += a.y + d.y + h.y;
                q.z += a.z + d.z + h.z; q.w += a.w + d.w + h.w;
            }
            float4 e;
            e.x = __expf(q.x); e.y = __expf(q.y);
            e.z = __expf(q.z); e.w = __expf(q.w);
#pragma unroll
            for (int t = 0; t < TOPICS; ++t) {
                float4 g = *(const float4*)(eb + (size_t)t * VOCAB + i * 4);
                acc[t] += e.x * g.x + e.y * g.y + e.z * g.z + e.w * g.w;
            }
        }
#pragma unroll
        for (int t = 0; t < TOPICS; ++t) {
            float v = acc[t];
            for (int off = 32; off; off >>= 1) v += __shfl_down(v, off, 64);
            if (lane == 0) red[w][t] = v;
        }
        __syncthreads();
        if (tid < TOPICS) {
            float s = red[0][tid] + red[1][tid] + red[2][tid] + red[3][tid];
            atomicAdd(&lsum[b * TOPICS + tid], s);
        }
    } else {
        float a = 0.f;
        for (int i = i0; i < VOCAB / 4; i += 4096) {
            float4 q = P0[i];
            if (!f32) {
                float4 x = P1[i], d = P2[i], h = P3[i];
                q.x += x.x + d.x + h.x; q.y += x.y + d.y + h.y;
                q.z += x.z + d.z + h.z; q.w += x.w + d.w + h.w;
            }
            a += __expf(q.x) + __expf(q.y) + __expf(q.z) + __expf(q.w);
        }
        for (int off = 32; off; off >>= 1) a += __shfl_down(a, off, 64);
        if (lane == 0) red[w][0] = a;
        __syncthreads();
        if (tid < TOPICS) {
            float s = red[0][0] + red[1][0] + red[2][0] + red[3][0];
            atomicAdd(&lsum[b * TOPICS + tid], s);
        }
    }
}

// ---------- D2: out[b][t][v] = exp(sum_kb p_kb) * (c ? eb[t][v] : 1) / lsum[b][t] ----------
template<bool F32>
__device__ void write_body(const float* esv4, const float* eb, const float* coeff,
                           const float* lsum, void* dout) {
    int b = blockIdx.y, tid = threadIdx.x;
    int v0 = blockIdx.x * 2048 + tid * 8;
    if (v0 >= VOCAB) return;
    float c = coeff[b];
    const float* er = esv4 + (size_t)b * VOCAB + v0;
    float4 q0 = *(const float4*)er;
    float4 q1 = *(const float4*)(er + 4);
    if constexpr (!F32) {            // bf16 path: sum 4 k-partials
#pragma unroll
        for (int p = 1; p < 4; ++p) {
            float4 a0 = *(const float4*)(er + p * ESV_PART);
            float4 a1 = *(const float4*)(er + p * ESV_PART + 4);
            q0.x += a0.x; q0.y += a0.y; q0.z += a0.z; q0.w += a0.w;
            q1.x += a1.x; q1.y += a1.y; q1.z += a1.z; q1.w += a1.w;
        }
    }
    float4 e0, e1;
    e0.x = __expf(q0.x); e0.y = __expf(q0.y); e0.z = __expf(q0.z); e0.w = __expf(q0.w);
    e1.x = __expf(q1.x); e1.y = __expf(q1.y); e1.z = __expf(q1.z); e1.w = __expf(q1.w);
#pragma unroll 4
    for (int t = 0; t < TOPICS; ++t) {
        float inv = 1.0f / lsum[b * TOPICS + t];
        float o0, o1, o2, o3, o4, o5, o6, o7;
        if (c != 0.f) {
            const float* gr = eb + (size_t)t * VOCAB + v0;
            float4 g0 = *(const float4*)gr;
            float4 g1 = *(const float4*)(gr + 4);
            o0 = e0.x * g0.x * inv; o1 = e0.y * g0.y * inv;
            o2 = e0.z * g0.z * inv; o3 = e0.w * g0.w * inv;
            o4 = e1.x * g1.x * inv; o5 = e1.y * g1.y * inv;
            o6 = e1.z * g1.z * inv; o7 = e1.w * g1.w * inv;
        } else {
            o0 = e0.x * inv; o1 = e0.y * inv; o2 = e0.z * inv; o3 = e0.w * inv;
            o4 = e1.x * inv; o5 = e1.y * inv; o6 = e1.z * inv; o7 = e1.w * inv;
        }
        size_t off = (size_t)b * TOPICS * VOCAB + (size_t)t * VOCAB + v0;
        if constexpr (F32) {
            float4 s0 = {o0, o1, o2, o3}, s1 = {o4, o5, o6, o7};
            *(float4*)((float*)dout + off) = s0;
            *(float4*)((float*)dout + off + 4) = s1;
        } else {
            uint4 st;
            st.x = (u32)f2bf(o0) | ((u32)f2bf(o1) << 16);
            st.y = (u32)f2bf(o2) | ((u32)f2bf(o3) << 16);
            st.z = (u32)f2bf(o4) | ((u32)f2bf(o5) << 16);
            st.w = (u32)f2bf(o6) | ((u32)f2bf(o7) << 16);
            *(uint4*)((u16*)dout + off) = st;
        }
    }
}
__global__ __launch_bounds__(256)
void k_write(const int* __restrict__ flag, const float* __restrict__ esv4,
             const float* __restrict__ eb, const float* __restrict__ coeff,
             const float* __restrict__ lsum, void* dout) {
    if (*flag) write_body<true>(esv4, eb, coeff, lsum, dout);
    else       write_body<false>(esv4, eb, coeff, lsum, dout);
}

extern "C" void kernel_launch(void* const* d_in, const int* in_sizes, int n_in,
                              void* d_out, int out_size, void* d_ws, size_t ws_size,
                              hipStream_t stream) {
    const void* xin  = d_in[0];
    const void* h0   = d_in[1];
    const void* Wxh  = d_in[2];
    const void* Whh  = d_in[3];
    const void* bk   = d_in[4];
    const void* Wv   = d_in[5];
    const void* beta = d_in[6];

    char* ws = (char*)d_ws;
    int*   flag   = (int*)  (ws + 0);
    float* coeff  = (float*)(ws + 256);
    float* lsum   = (float*)(ws + 1024);      // 1280 f -> ends 6144
    float* ns_f32 = (float*)(ws + 8192);      // 256 KiB -> ends 270336
    float* eb     = (float*)(ws + 270336);    // 2.56 MB -> ends 2830336
    float* esv4   = (float*)(ws + 2830336);   // 4 x 8.192 MB -> ends 35598336

    k_init <<<320, 256, 0, stream>>>(beta, flag, lsum, eb);
    k_state<<<256, 256, 0, stream>>>(flag, xin, h0, Wxh, Whh, ns_f32, d_out);
    k_bern <<<64, 64, 0, stream>>>(flag, ns_f32, bk, coeff);
    k_sv   <<<500, 256, 0, stream>>>(flag, ns_f32, Wv, d_out, esv4);
    k_sum  <<<dim3(16, 64), 256, 0, stream>>>(flag, esv4, eb, coeff, lsum);
    k_write<<<dim3(16, 64), 256, 0, stream>>>(flag, esv4, eb, coeff, lsum, d_out);
}